// Round 1
// baseline (337.834 us; speedup 1.0000x reference)
//
#include <hip/hip_runtime.h>
#include <cstdint>

// Y[m,n] = scale[n] * sum_k x[m,k]*(q[n,k]-zp[n]) + bias[n]
// M = B*S = 4096, N = 4096, K = 4096.
// (q-zp) is an integer in [-255,255] -> exact in bf16. Only x's bf16
// rounding contributes error (~0.13 sigma per output, threshold 18.08).

#define M_DIM 4096
#define N_DIM 4096
#define K_DIM 4096

typedef __bf16 v8bf __attribute__((ext_vector_type(8)));
typedef float  v4f  __attribute__((ext_vector_type(4)));

// Async global->LDS, 16B per lane. HW dest = wave-uniform base + lane*16;
// lane 0's pointer supplies the base, so LDS layout must be flat-contiguous
// in lane order (no padding).
static __device__ __forceinline__ void load_lds16(const void* g, void* l) {
    __builtin_amdgcn_global_load_lds(
        (__attribute__((address_space(1))) void*)(uintptr_t)g,
        (__attribute__((address_space(3))) void*)(uint32_t)(uintptr_t)l,
        16, 0, 0);
}

// ---- prep: x fp32 -> bf16 (8 elems/thread) ----
__global__ __launch_bounds__(256) void cvt_x_k(const float4* __restrict__ x,
                                               v8bf* __restrict__ o) {
    const int i = blockIdx.x * 256 + threadIdx.x;
    const float4 a = x[2 * i];
    const float4 b = x[2 * i + 1];
    v8bf v;
    v[0] = (__bf16)a.x; v[1] = (__bf16)a.y; v[2] = (__bf16)a.z; v[3] = (__bf16)a.w;
    v[4] = (__bf16)b.x; v[5] = (__bf16)b.y; v[6] = (__bf16)b.z; v[7] = (__bf16)b.w;
    o[i] = v;
}

// ---- prep: (q - zp[n]) int32 -> bf16 exact (8 elems/thread) ----
__global__ __launch_bounds__(256) void cvt_w_k(const int4* __restrict__ q,
                                               const int* __restrict__ zp,
                                               v8bf* __restrict__ o) {
    const int i = blockIdx.x * 256 + threadIdx.x;
    const int n = (i * 8) >> 12;           // / K_DIM, uniform per 512 threads
    const int z = zp[n];
    const int4 a = q[2 * i];
    const int4 b = q[2 * i + 1];
    v8bf v;
    v[0] = (__bf16)(float)(a.x - z); v[1] = (__bf16)(float)(a.y - z);
    v[2] = (__bf16)(float)(a.z - z); v[3] = (__bf16)(float)(a.w - z);
    v[4] = (__bf16)(float)(b.x - z); v[5] = (__bf16)(float)(b.y - z);
    v[6] = (__bf16)(float)(b.z - z); v[7] = (__bf16)(float)(b.w - z);
    o[i] = v;
}

// ---- main: C = A(MxK) . B(NxK)^T, 128x128 tile, BK=32, m97 structure ----
// A, B row-major bf16, K-major (gemm_bt). Epilogue: C = acc*scale[n]+bias[n].
__global__ __launch_bounds__(256) void gemm_bt(
    const __bf16* __restrict__ A, const __bf16* __restrict__ B,
    const float* __restrict__ scales, const float* __restrict__ bias,
    float* __restrict__ C)
{
    __shared__ __bf16 As[128 * 32];   // 8 KiB, flat [row][k], row stride 32
    __shared__ __bf16 Bs[128 * 32];   // 8 KiB

    const int tid  = threadIdx.x;
    const int lane = tid & 63;
    const int wave = tid >> 6;
    const int waveM = (wave & 1) * 64;     // 2x2 waves, each 64x64
    const int waveN = (wave >> 1) * 64;
    const int mBase = blockIdx.y * 128;
    const int nBase = blockIdx.x * 128;

    // staging map: thread t loads row (issue*64 + t/4), k-cols [(t&3)*8, +8)
    const int rA = tid >> 2;
    const int cA = (tid & 3) * 8;
    const __bf16* gA0 = A + (size_t)(mBase + rA) * K_DIM + cA;
    const __bf16* gA1 = gA0 + (size_t)64 * K_DIM;
    const __bf16* gB0 = B + (size_t)(nBase + rA) * K_DIM + cA;
    const __bf16* gB1 = gB0 + (size_t)64 * K_DIM;
    char* lA0 = (char*)As + tid * 16;
    char* lA1 = lA0 + 4096;
    char* lB0 = (char*)Bs + tid * 16;
    char* lB1 = lB0 + 4096;

    // fragment read map: A[m=lane&15][k=(lane>>4)*8+j] (same for B rows=n)
    const int quad = lane >> 4;
    const int r16  = lane & 15;
    const __bf16* aRd = As + (waveM + r16) * 32 + quad * 8;
    const __bf16* bRd = Bs + (waveN + r16) * 32 + quad * 8;

    v4f acc[4][4];
    #pragma unroll
    for (int i = 0; i < 4; ++i)
        #pragma unroll
        for (int j = 0; j < 4; ++j)
            acc[i][j] = v4f{0.f, 0.f, 0.f, 0.f};

    for (int k0 = 0; k0 < K_DIM; k0 += 32) {
        load_lds16(gA0, lA0);
        load_lds16(gA1, lA1);
        load_lds16(gB0, lB0);
        load_lds16(gB1, lB1);
        gA0 += 32; gA1 += 32; gB0 += 32; gB1 += 32;
        __syncthreads();   // compiler emits vmcnt(0) drain before barrier

        v8bf af[4], bfr[4];
        #pragma unroll
        for (int i = 0; i < 4; ++i)
            af[i] = *(const v8bf*)(aRd + i * 16 * 32);   // ds_read_b128
        #pragma unroll
        for (int j = 0; j < 4; ++j)
            bfr[j] = *(const v8bf*)(bRd + j * 16 * 32);
        #pragma unroll
        for (int i = 0; i < 4; ++i)
            #pragma unroll
            for (int j = 0; j < 4; ++j)
                acc[i][j] = __builtin_amdgcn_mfma_f32_16x16x32_bf16(
                    af[i], bfr[j], acc[i][j], 0, 0, 0);
        __syncthreads();
    }

    // C/D layout (16x16x32): col = lane&15, row = (lane>>4)*4 + reg
    #pragma unroll
    for (int j = 0; j < 4; ++j) {
        const int col = nBase + waveN + j * 16 + r16;
        const float s  = scales[col];
        const float bv = bias[col];
        #pragma unroll
        for (int i = 0; i < 4; ++i) {
            const int row0 = mBase + waveM + i * 16 + quad * 4;
            #pragma unroll
            for (int r = 0; r < 4; ++r)
                C[(size_t)(row0 + r) * N_DIM + col] = acc[i][j][r] * s + bv;
        }
    }
}

// ---- fallback (only if ws_size < 64 MiB): plain fp32 tiled GEMM ----
__global__ __launch_bounds__(256) void gemm_fb(
    const float* __restrict__ X, const int* __restrict__ Q,
    const float* __restrict__ SC, const int* __restrict__ ZP,
    const float* __restrict__ BI, float* __restrict__ C)
{
    __shared__ float Xs[64][17];
    __shared__ float Ws[64][17];
    const int tx = threadIdx.x & 15, ty = threadIdx.x >> 4;
    const int m0 = blockIdx.y * 64, n0 = blockIdx.x * 64;
    float acc[4][4] = {};
    for (int k0 = 0; k0 < K_DIM; k0 += 16) {
        for (int t = threadIdx.x; t < 64 * 16; t += 256) {
            const int r = t >> 4, c = t & 15;
            Xs[r][c] = X[(size_t)(m0 + r) * K_DIM + k0 + c];
            const int n = n0 + r;
            Ws[r][c] = (float)(Q[(size_t)n * K_DIM + k0 + c] - ZP[n]);
        }
        __syncthreads();
        #pragma unroll
        for (int kk = 0; kk < 16; ++kk) {
            float a[4], b[4];
            #pragma unroll
            for (int i = 0; i < 4; ++i) a[i] = Xs[ty * 4 + i][kk];
            #pragma unroll
            for (int j = 0; j < 4; ++j) b[j] = Ws[tx * 4 + j][kk];
            #pragma unroll
            for (int i = 0; i < 4; ++i)
                #pragma unroll
                for (int j = 0; j < 4; ++j)
                    acc[i][j] += a[i] * b[j];
        }
        __syncthreads();
    }
    #pragma unroll
    for (int j = 0; j < 4; ++j) {
        const int n = n0 + tx * 4 + j;
        const float s = SC[n], bv = BI[n];
        #pragma unroll
        for (int i = 0; i < 4; ++i)
            C[(size_t)(m0 + ty * 4 + i) * N_DIM + n] = acc[i][j] * s + bv;
    }
}

extern "C" void kernel_launch(void* const* d_in, const int* in_sizes, int n_in,
                              void* d_out, int out_size, void* d_ws, size_t ws_size,
                              hipStream_t stream) {
    const float* x  = (const float*)d_in[0];
    const int*   qw = (const int*)d_in[1];
    const float* sc = (const float*)d_in[2];
    const int*   zp = (const int*)d_in[3];
    const float* bi = (const float*)d_in[4];
    float* out = (float*)d_out;

    const size_t MK = (size_t)M_DIM * K_DIM;            // 16,777,216
    const size_t need = MK * 2 * 2;                     // 64 MiB (bf16 A + bf16 W)

    if (ws_size >= need) {
        __bf16* xb = (__bf16*)d_ws;
        __bf16* wb = xb + MK;
        cvt_x_k<<<8192, 256, 0, stream>>>((const float4*)x, (v8bf*)xb);
        cvt_w_k<<<8192, 256, 0, stream>>>((const int4*)qw, zp, (v8bf*)wb);
        gemm_bt<<<dim3(32, 32), 256, 0, stream>>>(xb, wb, sc, bi, out);
    } else {
        gemm_fb<<<dim3(64, 64), 256, 0, stream>>>(x, qw, sc, zp, bi, out);
    }
}